// Round 9
// baseline (617.699 us; speedup 1.0000x reference)
//
#include <hip/hip_runtime.h>
#include <hip/hip_bf16.h>
#include <math.h>

#define DIM 64

typedef _Float16 half_t;
typedef __attribute__((ext_vector_type(8))) _Float16 half8;
typedef __attribute__((ext_vector_type(4))) _Float16 h16x4;
typedef __attribute__((ext_vector_type(4))) float f32x4;

__device__ __forceinline__ half8 hmax8(half8 a, half8 b) {
    return __builtin_elementwise_max(a, b);   // v_pk_max_f16
}

// ---------------- CSR build (bucket-local; pairs packed src<<9 | dst&511) ----------------

__global__ void kbcnt(const int* __restrict__ ei, int E, int* __restrict__ gcnt) {
    __shared__ int h[256];
    int t = threadIdx.x;
    h[t] = 0;
    __syncthreads();
    for (int e = blockIdx.x * 256 + t; e < E; e += gridDim.x * 256)
        atomicAdd(&h[ei[E + e] >> 9], 1);
    __syncthreads();
    if (h[t]) atomicAdd(&gcnt[t], h[t]);
}

__global__ void kbscan(const int* __restrict__ gcnt, int* __restrict__ gbs,
                       int* __restrict__ gbc, int NB, int E,
                       int* __restrict__ rs, int N) {
    __shared__ int sm[256];
    int t = threadIdx.x;
    int v = (t < NB) ? gcnt[t] : 0;
    sm[t] = v;
    __syncthreads();
    for (int off = 1; off < 256; off <<= 1) {
        int add = (t >= off) ? sm[t - off] : 0;
        __syncthreads();
        sm[t] += add;
        __syncthreads();
    }
    int excl = sm[t] - v;
    if (t < NB) { gbs[t] = excl; gbc[t] = excl; }
    if (t == NB - 1) gbs[NB] = excl + v;    // == E
    if (t == 0) rs[N] = E;
}

__global__ void kbin(const int* __restrict__ ei, int E,
                     int* __restrict__ gbc, int* __restrict__ pairs, int NB) {
    __shared__ int hist[256];
    __shared__ int basep[256];
    const int t = threadIdx.x;
    const int c0 = blockIdx.x * 4096;
    hist[t] = 0;
    __syncthreads();
    int s[16], d[16];
#pragma unroll
    for (int i = 0; i < 16; ++i) {
        int e = c0 + i * 256 + t;
        if (e < E) {
            s[i] = ei[e];
            d[i] = ei[E + e];
            atomicAdd(&hist[d[i] >> 9], 1);
        } else d[i] = -1;
    }
    __syncthreads();
    if (t < NB) {
        basep[t] = atomicAdd(&gbc[t], hist[t]);
        hist[t] = 0;
    }
    __syncthreads();
#pragma unroll
    for (int i = 0; i < 16; ++i) {
        if (d[i] >= 0) {
            int b = d[i] >> 9;
            int off = atomicAdd(&hist[b], 1);
            pairs[basep[b] + off] = (s[i] << 9) | (d[i] & 511);
        }
    }
}

// ssrc stores BYTE offsets (src * 128) for the fp16 row gather.
__global__ void __launch_bounds__(256) kfinal(
        const int* __restrict__ pairs, const int* __restrict__ gbs,
        int* __restrict__ rs, int* __restrict__ ssrc, int N) {
    __shared__ int lcnt[512];
    __shared__ int lcur[512];
    __shared__ int ps[256];
    const int b = blockIdx.x;
    const int t = threadIdx.x;
    const int n0 = b << 9;
    const int e0 = gbs[b], e1 = gbs[b + 1];
    lcnt[t] = 0;
    lcnt[t + 256] = 0;
    __syncthreads();
    for (int e = e0 + t; e < e1; e += 256)
        atomicAdd(&lcnt[pairs[e] & 511], 1);
    __syncthreads();
    int c0 = lcnt[2 * t], c1 = lcnt[2 * t + 1];
    int sum = c0 + c1;
    ps[t] = sum;
    __syncthreads();
    for (int off = 1; off < 256; off <<= 1) {
        int add = (t >= off) ? ps[t - off] : 0;
        __syncthreads();
        ps[t] += add;
        __syncthreads();
    }
    int excl = ps[t] - sum;
    lcur[2 * t] = excl;
    lcur[2 * t + 1] = excl + c0;
    int n = n0 + 2 * t;
    if (n < N) rs[n] = e0 + excl;
    if (n + 1 < N) rs[n + 1] = e0 + excl + c0;
    __syncthreads();
    for (int e = e0 + t; e < e1; e += 256) {
        int p = pairs[e];
        int pos = atomicAdd(&lcur[p & 511], 1);
        ssrc[e0 + pos] = (int)((unsigned)p >> 9) << 7;   // byte offset of fp16 row
    }
}

// ---------------- fp32 x -> fp16 plane ----------------

__global__ void kcvt(const float* __restrict__ x, half_t* __restrict__ phi, int n4) {
    int i = blockIdx.x * blockDim.x + threadIdx.x;
    if (i < n4) {
        f32x4 v = ((const f32x4*)x)[i];
        h16x4 hi;
#pragma unroll
        for (int c = 0; c < 4; ++c) hi[c] = (half_t)v[c];
        ((h16x4*)phi)[i] = hi;
    }
}

// ---------------- weight prep: fp16 hi/lo MFMA B-fragments ----------------
// B[k][j], k in [0,128): k<64 -> Wl[j][k]; k>=64 -> Wr[j][k-64]
// frag f = (s*4+t)*2 (+1 for lo); element [lane][i]: k = s*32+(lane>>4)*8+i, j = t*16+(lane&15)

__global__ void kprepw(const float* __restrict__ Wl, const float* __restrict__ Wr,
                       half_t* __restrict__ Bf) {
    int id = blockIdx.x * blockDim.x + threadIdx.x;
    if (id >= 6 * 4 * 4 * 64 * 8) return;
    int i = id & 7;
    int lane = (id >> 3) & 63;
    int t = (id >> 9) & 3;
    int s = (id >> 11) & 3;
    int layer = id >> 13;
    int k = s * 32 + (lane >> 4) * 8 + i;
    int j = t * 16 + (lane & 15);
    float v = (k < 64) ? Wl[(layer * 64 + j) * 64 + k]
                       : Wr[(layer * 64 + j) * 64 + (k - 64)];
    half_t hi = (half_t)v;
    half_t lo = (half_t)(v - (float)hi);
    int f = (s * 4 + t) * 2;
    int base = layer * 16384 + f * 512 + lane * 8 + i;
    Bf[base] = hi;
    Bf[base + 512] = lo;
}

// ---------------- fused layer: gather-max straight into MFMA A-frags + GEMM ----------------
// lane (lrow=lane&15, quad=lane>>4) owns node row m0+lrow, k-slices [quad*8,quad*8+8) and
// [32+quad*8, ...). Degree loop is per-lane divergent (no cross-lane ops inside — safe).

__global__ void __launch_bounds__(256, 4) klayer(
        const half_t* __restrict__ hin, const int* __restrict__ rs,
        const int* __restrict__ soff, const half_t* __restrict__ Bf,
        const float* __restrict__ bias, half_t* __restrict__ hout,
        float* __restrict__ out32, int N, int last) {
    __shared__ half8 Bs[2048];   // 32 KB: 32 frags x 64 lanes x 16B
    const int tid = threadIdx.x;
    const half8* __restrict__ Bg = (const half8*)Bf;
#pragma unroll
    for (int i = 0; i < 8; ++i) Bs[i * 256 + tid] = Bg[i * 256 + tid];
    __syncthreads();

    const int lane = tid & 63;
    const int quad = lane >> 4;
    const int lrow = lane & 15;
    const int wv = (blockIdx.x * blockDim.x + tid) >> 6;
    const int nwv = (gridDim.x * blockDim.x) >> 6;
    const int ntiles = (N + 15) >> 4;
    const char* hb = (const char*)hin + quad * 16;   // this lane's k-slice base

    float bs_[4];
#pragma unroll
    for (int t = 0; t < 4; ++t) bs_[t] = bias[t * 16 + lrow];

    const half_t NEG = (half_t)(-65504.0f);
    const half8 NEG8 = {NEG, NEG, NEG, NEG, NEG, NEG, NEG, NEG};
    const half8 Z8 = {(half_t)0.f, (half_t)0.f, (half_t)0.f, (half_t)0.f,
                      (half_t)0.f, (half_t)0.f, (half_t)0.f, (half_t)0.f};

    for (int tile = wv; tile < ntiles; tile += nwv) {
        const int m0 = tile << 4;
        int row = m0 + lrow;
        if (row >= N) row = N - 1;       // N%16==0 in practice
        int beg = rs[row], end = rs[row + 1];
        int lastE = end - 1;

        half8 a0 = NEG8, a1 = NEG8, b0 = NEG8, b1 = NEG8;
        half8 c0 = NEG8, c1 = NEG8, d0 = NEG8, d1 = NEG8;
        for (int e = beg; e < end; e += 4) {     // per-lane divergent, idempotent clamp
            int e1 = (e + 1 <= lastE) ? e + 1 : lastE;
            int e2 = (e + 2 <= lastE) ? e + 2 : lastE;
            int e3 = (e + 3 <= lastE) ? e + 3 : lastE;
            int o0 = soff[e], o1 = soff[e1], o2 = soff[e2], o3 = soff[e3];
            a0 = hmax8(a0, *(const half8*)(hb + o0));
            a1 = hmax8(a1, *(const half8*)(hb + o0 + 64));
            b0 = hmax8(b0, *(const half8*)(hb + o1));
            b1 = hmax8(b1, *(const half8*)(hb + o1 + 64));
            c0 = hmax8(c0, *(const half8*)(hb + o2));
            c1 = hmax8(c1, *(const half8*)(hb + o2 + 64));
            d0 = hmax8(d0, *(const half8*)(hb + o3));
            d1 = hmax8(d1, *(const half8*)(hb + o3 + 64));
        }
        half8 A0 = hmax8(hmax8(a0, b0), hmax8(c0, d0));
        half8 A1 = hmax8(hmax8(a1, b1), hmax8(c1, d1));
        if (end <= beg) { A0 = Z8; A1 = Z8; }    // no in-edges -> 0

        const char* ph = (const char*)hin + (size_t)row * 128 + quad * 16;
        half8 H0 = *(const half8*)(ph);
        half8 H1 = *(const half8*)(ph + 64);

        f32x4 acc[4] = {{0.f, 0.f, 0.f, 0.f}, {0.f, 0.f, 0.f, 0.f},
                        {0.f, 0.f, 0.f, 0.f}, {0.f, 0.f, 0.f, 0.f}};
#pragma unroll
        for (int t = 0; t < 4; ++t) {
            acc[t] = __builtin_amdgcn_mfma_f32_16x16x32_f16(A0, Bs[((0 * 4 + t) * 2 + 0) * 64 + lane], acc[t], 0, 0, 0);
            acc[t] = __builtin_amdgcn_mfma_f32_16x16x32_f16(A0, Bs[((0 * 4 + t) * 2 + 1) * 64 + lane], acc[t], 0, 0, 0);
            acc[t] = __builtin_amdgcn_mfma_f32_16x16x32_f16(A1, Bs[((1 * 4 + t) * 2 + 0) * 64 + lane], acc[t], 0, 0, 0);
            acc[t] = __builtin_amdgcn_mfma_f32_16x16x32_f16(A1, Bs[((1 * 4 + t) * 2 + 1) * 64 + lane], acc[t], 0, 0, 0);
            acc[t] = __builtin_amdgcn_mfma_f32_16x16x32_f16(H0, Bs[((2 * 4 + t) * 2 + 0) * 64 + lane], acc[t], 0, 0, 0);
            acc[t] = __builtin_amdgcn_mfma_f32_16x16x32_f16(H0, Bs[((2 * 4 + t) * 2 + 1) * 64 + lane], acc[t], 0, 0, 0);
            acc[t] = __builtin_amdgcn_mfma_f32_16x16x32_f16(H1, Bs[((3 * 4 + t) * 2 + 0) * 64 + lane], acc[t], 0, 0, 0);
            acc[t] = __builtin_amdgcn_mfma_f32_16x16x32_f16(H1, Bs[((3 * 4 + t) * 2 + 1) * 64 + lane], acc[t], 0, 0, 0);
        }

        // C/D: col = t*16 + lrow, row = m0 + quad*4 + r
#pragma unroll
        for (int t = 0; t < 4; ++t) {
            int col = t * 16 + lrow;
#pragma unroll
            for (int r = 0; r < 4; ++r) {
                int orow = m0 + quad * 4 + r;
                if (orow < N) {
                    float v = acc[t][r] + bs_[t];
                    if (!last) {
                        v = fmaxf(v, 0.0f);
                        hout[(size_t)orow * DIM + col] = (half_t)v;
                    } else {
                        out32[(size_t)orow * DIM + col] = v;
                    }
                }
            }
        }
    }
}

// ---------------- host ----------------

extern "C" void kernel_launch(void* const* d_in, const int* in_sizes, int n_in,
                              void* d_out, int out_size, void* d_ws, size_t ws_size,
                              hipStream_t stream) {
    const float* x  = (const float*)d_in[0];
    const int*   ei = (const int*)d_in[1];
    const float* Wl = (const float*)d_in[2];
    const float* bl = (const float*)d_in[3];
    const float* Wr = (const float*)d_in[4];
    int N = in_sizes[0] / DIM;
    int E = in_sizes[1] / 2;

    size_t nd = (size_t)N * DIM;
    half_t* p0    = (half_t*)d_ws;           // fp16 h plane ping
    half_t* p1    = p0 + nd;                 // fp16 h plane pong; aliased as `pairs` during CSR build
    int*    rs    = (int*)(p1 + nd);         // N+1 used, N+4 reserved
    int*    ssrc  = rs + (N + 4);            // byte offsets
    int*    gcnt  = ssrc + E;                // 256
    int*    gbs   = gcnt + 256;              // NB+1 (260 reserved)
    int*    gbc   = gbs + 260;               // 256
    half_t* Bf    = (half_t*)(gbc + 256);    // 6 layers * 16384 halfs

    int NB = (N + 511) >> 9;                 // 196 for N=100000
    int* pairs = (int*)p1;                   // consumed by kfinal before layer 0 writes p1

    hipMemsetAsync(gcnt, 0, 256 * sizeof(int), stream);
    kbcnt<<<640, 256, 0, stream>>>(ei, E, gcnt);
    kbscan<<<1, 256, 0, stream>>>(gcnt, gbs, gbc, NB, E, rs, N);
    kbin<<<(E + 4095) / 4096, 256, 0, stream>>>(ei, E, gbc, pairs, NB);
    kfinal<<<NB, 256, 0, stream>>>(pairs, gbs, rs, ssrc, N);
    kprepw<<<(6 * 4 * 4 * 64 * 8 + 255) / 256, 256, 0, stream>>>(Wl, Wr, Bf);
    kcvt<<<((int)(nd / 4) + 255) / 256, 256, 0, stream>>>(x, p0, (int)(nd / 4));

    for (int l = 0; l < 6; ++l) {
        half_t* ih = (l & 1) ? p1 : p0;
        half_t* oh = (l & 1) ? p0 : p1;
        int last = (l == 5);
        klayer<<<1024, 256, 0, stream>>>(ih, rs, ssrc, Bf + l * 16384, bl + l * 64,
                                         oh, (float*)d_out, N, last);
    }
}

// Round 10
// 390.461 us; speedup vs baseline: 1.5820x; 1.5820x over previous
//
#include <hip/hip_runtime.h>
#include <hip/hip_bf16.h>
#include <math.h>

#define DIM 64

typedef _Float16 half_t;
typedef __attribute__((ext_vector_type(8))) _Float16 half8;
typedef __attribute__((ext_vector_type(4))) _Float16 h16x4;
typedef __attribute__((ext_vector_type(4))) float f32x4;

__device__ __forceinline__ half8 hmax8(half8 a, half8 b) {
    return __builtin_elementwise_max(a, b);   // v_pk_max_f16
}

// ---------------- CSR build (bucket-local; pairs packed src<<9 | dst&511) ----------------

__global__ void kbcnt(const int* __restrict__ ei, int E, int* __restrict__ gcnt) {
    __shared__ int h[256];
    int t = threadIdx.x;
    h[t] = 0;
    __syncthreads();
    for (int e = blockIdx.x * 256 + t; e < E; e += gridDim.x * 256)
        atomicAdd(&h[ei[E + e] >> 9], 1);
    __syncthreads();
    if (h[t]) atomicAdd(&gcnt[t], h[t]);
}

__global__ void kbscan(const int* __restrict__ gcnt, int* __restrict__ gbs,
                       int* __restrict__ gbc, int NB, int E,
                       int* __restrict__ rs, int N) {
    __shared__ int sm[256];
    int t = threadIdx.x;
    int v = (t < NB) ? gcnt[t] : 0;
    sm[t] = v;
    __syncthreads();
    for (int off = 1; off < 256; off <<= 1) {
        int add = (t >= off) ? sm[t - off] : 0;
        __syncthreads();
        sm[t] += add;
        __syncthreads();
    }
    int excl = sm[t] - v;
    if (t < NB) { gbs[t] = excl; gbc[t] = excl; }
    if (t == NB - 1) gbs[NB] = excl + v;    // == E
    if (t == 0) rs[N] = E;
}

__global__ void kbin(const int* __restrict__ ei, int E,
                     int* __restrict__ gbc, int* __restrict__ pairs, int NB) {
    __shared__ int hist[256];
    __shared__ int basep[256];
    const int t = threadIdx.x;
    const int c0 = blockIdx.x * 4096;
    hist[t] = 0;
    __syncthreads();
    int s[16], d[16];
#pragma unroll
    for (int i = 0; i < 16; ++i) {
        int e = c0 + i * 256 + t;
        if (e < E) {
            s[i] = ei[e];
            d[i] = ei[E + e];
            atomicAdd(&hist[d[i] >> 9], 1);
        } else d[i] = -1;
    }
    __syncthreads();
    if (t < NB) {
        basep[t] = atomicAdd(&gbc[t], hist[t]);
        hist[t] = 0;
    }
    __syncthreads();
#pragma unroll
    for (int i = 0; i < 16; ++i) {
        if (d[i] >= 0) {
            int b = d[i] >> 9;
            int off = atomicAdd(&hist[b], 1);
            pairs[basep[b] + off] = (s[i] << 9) | (d[i] & 511);
        }
    }
}

// ssrc stores BYTE offsets (src * 128) for the fp16 row gather.
__global__ void __launch_bounds__(256) kfinal(
        const int* __restrict__ pairs, const int* __restrict__ gbs,
        int* __restrict__ rs, int* __restrict__ ssrc, int N) {
    __shared__ int lcnt[512];
    __shared__ int lcur[512];
    __shared__ int ps[256];
    const int b = blockIdx.x;
    const int t = threadIdx.x;
    const int n0 = b << 9;
    const int e0 = gbs[b], e1 = gbs[b + 1];
    lcnt[t] = 0;
    lcnt[t + 256] = 0;
    __syncthreads();
    for (int e = e0 + t; e < e1; e += 256)
        atomicAdd(&lcnt[pairs[e] & 511], 1);
    __syncthreads();
    int c0 = lcnt[2 * t], c1 = lcnt[2 * t + 1];
    int sum = c0 + c1;
    ps[t] = sum;
    __syncthreads();
    for (int off = 1; off < 256; off <<= 1) {
        int add = (t >= off) ? ps[t - off] : 0;
        __syncthreads();
        ps[t] += add;
        __syncthreads();
    }
    int excl = ps[t] - sum;
    lcur[2 * t] = excl;
    lcur[2 * t + 1] = excl + c0;
    int n = n0 + 2 * t;
    if (n < N) rs[n] = e0 + excl;
    if (n + 1 < N) rs[n + 1] = e0 + excl + c0;
    __syncthreads();
    for (int e = e0 + t; e < e1; e += 256) {
        int p = pairs[e];
        int pos = atomicAdd(&lcur[p & 511], 1);
        ssrc[e0 + pos] = (int)((unsigned)p >> 9) << 7;   // byte offset of fp16 row
    }
}

// ---------------- fp32 x -> fp16 plane ----------------

__global__ void kcvt(const float* __restrict__ x, half_t* __restrict__ phi, int n4) {
    int i = blockIdx.x * blockDim.x + threadIdx.x;
    if (i < n4) {
        f32x4 v = ((const f32x4*)x)[i];
        h16x4 hi;
#pragma unroll
        for (int c = 0; c < 4; ++c) hi[c] = (half_t)v[c];
        ((h16x4*)phi)[i] = hi;
    }
}

// ---------------- weight prep: fp16 hi/lo MFMA B-fragments ----------------
// B[k][j], k in [0,128): k<64 -> Wl[j][k]; k>=64 -> Wr[j][k-64]
// frag f = (s*4+t)*2 (+1 for lo); element [lane][i]: k = s*32+(lane>>4)*8+i, j = t*16+(lane&15)

__global__ void kprepw(const float* __restrict__ Wl, const float* __restrict__ Wr,
                       half_t* __restrict__ Bf) {
    int id = blockIdx.x * blockDim.x + threadIdx.x;
    if (id >= 6 * 4 * 4 * 64 * 8) return;
    int i = id & 7;
    int lane = (id >> 3) & 63;
    int t = (id >> 9) & 3;
    int s = (id >> 11) & 3;
    int layer = id >> 13;
    int k = s * 32 + (lane >> 4) * 8 + i;
    int j = t * 16 + (lane & 15);
    float v = (k < 64) ? Wl[(layer * 64 + j) * 64 + k]
                       : Wr[(layer * 64 + j) * 64 + (k - 64)];
    half_t hi = (half_t)v;
    half_t lo = (half_t)(v - (float)hi);
    int f = (s * 4 + t) * 2;
    int base = layer * 16384 + f * 512 + lane * 8 + i;
    Bf[base] = hi;
    Bf[base + 512] = lo;
}

// ---------------- aggregation: lane-private (no cross-lane ops at all) ----------------
// lane (r=lane>>3, sub=lane&7) owns the 16B slice `sub` of node row wave*8+r.
// Per-lane divergent degree loop is safe: no shfl/ballot inside.
// One wave-load instruction covers 8 edges x 128B rows; stores are 1KB contiguous.

__global__ void __launch_bounds__(256) kagg(
        const half_t* __restrict__ h16, const int* __restrict__ rs,
        const int* __restrict__ soff, half_t* __restrict__ agg16, int N) {
    int lane = threadIdx.x & 63;
    int wv = (blockIdx.x * blockDim.x + threadIdx.x) >> 6;
    int row = wv * 8 + (lane >> 3);
    int sub = lane & 7;
    if (row >= N) return;
    const char* hb = (const char*)h16 + sub * 16;
    int beg = rs[row], end = rs[row + 1];
    int lastE = end - 1;
    const half_t NEG = (half_t)(-65504.0f);
    half8 m0 = {NEG, NEG, NEG, NEG, NEG, NEG, NEG, NEG};
    half8 m1 = m0, m2 = m0, m3 = m0;
    for (int e = beg; e < end; e += 4) {        // clamped unroll-4: re-max of a seen edge is a no-op
        int e1 = (e + 1 <= lastE) ? e + 1 : lastE;
        int e2 = (e + 2 <= lastE) ? e + 2 : lastE;
        int e3 = (e + 3 <= lastE) ? e + 3 : lastE;
        int o0 = soff[e], o1 = soff[e1], o2 = soff[e2], o3 = soff[e3];
        m0 = hmax8(m0, *(const half8*)(hb + o0));
        m1 = hmax8(m1, *(const half8*)(hb + o1));
        m2 = hmax8(m2, *(const half8*)(hb + o2));
        m3 = hmax8(m3, *(const half8*)(hb + o3));
    }
    half8 m = hmax8(hmax8(m0, m1), hmax8(m2, m3));
    if (end <= beg) {
        half8 z = {(half_t)0.f, (half_t)0.f, (half_t)0.f, (half_t)0.f,
                   (half_t)0.f, (half_t)0.f, (half_t)0.f, (half_t)0.f};
        m = z;                                  // no in-edges -> 0 (PyG convention)
    }
    *(half8*)((char*)agg16 + (size_t)row * 128 + sub * 16) = m;
}

// ---------------- fused GEMM: fp16 A (agg + h), fp16 hi/lo weights, 32 MFMA ----------------

__global__ void __launch_bounds__(256, 2) kgemm(
        const half_t* __restrict__ agg16, const half_t* __restrict__ hin,
        const half_t* __restrict__ Bf, const float* __restrict__ bias,
        float* __restrict__ out32, half_t* __restrict__ hout, int N, int last) {
    const int lane = threadIdx.x & 63;
    const int quad = lane >> 4;
    const int lrow = lane & 15;
    const int wv = (blockIdx.x * blockDim.x + threadIdx.x) >> 6;
    const int nwv = (gridDim.x * blockDim.x) >> 6;
    const int ntiles = (N + 15) >> 4;

    const half8* __restrict__ Bp = (const half8*)Bf;
    half8 bh[4][4], bl[4][4];
#pragma unroll
    for (int s = 0; s < 4; ++s)
#pragma unroll
        for (int t = 0; t < 4; ++t) {
            int f = (s * 4 + t) * 2;
            bh[s][t] = Bp[f * 64 + lane];
            bl[s][t] = Bp[f * 64 + 64 + lane];
        }

    float bs[4];
#pragma unroll
    for (int t = 0; t < 4; ++t) bs[t] = bias[t * 16 + lrow];

    for (int tile = wv; tile < ntiles; tile += nwv) {
        const int m0 = tile << 4;
        int row = m0 + lrow;
        if (row >= N) row = N - 1;
        const char* pa = (const char*)agg16 + (size_t)row * 128 + quad * 16;
        const char* ph = (const char*)hin   + (size_t)row * 128 + quad * 16;
        half8 Aa0 = *(const half8*)(pa);
        half8 Aa1 = *(const half8*)(pa + 64);
        half8 Hh0 = *(const half8*)(ph);
        half8 Hh1 = *(const half8*)(ph + 64);

        f32x4 acc[4] = {{0.f, 0.f, 0.f, 0.f}, {0.f, 0.f, 0.f, 0.f},
                        {0.f, 0.f, 0.f, 0.f}, {0.f, 0.f, 0.f, 0.f}};
#pragma unroll
        for (int t = 0; t < 4; ++t) {
            acc[t] = __builtin_amdgcn_mfma_f32_16x16x32_f16(Aa0, bh[0][t], acc[t], 0, 0, 0);
            acc[t] = __builtin_amdgcn_mfma_f32_16x16x32_f16(Aa0, bl[0][t], acc[t], 0, 0, 0);
            acc[t] = __builtin_amdgcn_mfma_f32_16x16x32_f16(Aa1, bh[1][t], acc[t], 0, 0, 0);
            acc[t] = __builtin_amdgcn_mfma_f32_16x16x32_f16(Aa1, bl[1][t], acc[t], 0, 0, 0);
            acc[t] = __builtin_amdgcn_mfma_f32_16x16x32_f16(Hh0, bh[2][t], acc[t], 0, 0, 0);
            acc[t] = __builtin_amdgcn_mfma_f32_16x16x32_f16(Hh0, bl[2][t], acc[t], 0, 0, 0);
            acc[t] = __builtin_amdgcn_mfma_f32_16x16x32_f16(Hh1, bh[3][t], acc[t], 0, 0, 0);
            acc[t] = __builtin_amdgcn_mfma_f32_16x16x32_f16(Hh1, bl[3][t], acc[t], 0, 0, 0);
        }

        // C/D: col = t*16 + lrow, row = m0 + quad*4 + r
#pragma unroll
        for (int t = 0; t < 4; ++t) {
            int col = t * 16 + lrow;
#pragma unroll
            for (int r = 0; r < 4; ++r) {
                int orow = m0 + quad * 4 + r;
                if (orow < N) {
                    float v = acc[t][r] + bs[t];
                    if (!last) {
                        v = fmaxf(v, 0.0f);
                        hout[(size_t)orow * DIM + col] = (half_t)v;
                    } else {
                        out32[(size_t)orow * DIM + col] = v;
                    }
                }
            }
        }
    }
}

// ---------------- host ----------------

extern "C" void kernel_launch(void* const* d_in, const int* in_sizes, int n_in,
                              void* d_out, int out_size, void* d_ws, size_t ws_size,
                              hipStream_t stream) {
    const float* x  = (const float*)d_in[0];
    const int*   ei = (const int*)d_in[1];
    const float* Wl = (const float*)d_in[2];
    const float* bl = (const float*)d_in[3];
    const float* Wr = (const float*)d_in[4];
    int N = in_sizes[0] / DIM;
    int E = in_sizes[1] / 2;

    size_t nd = (size_t)N * DIM;
    half_t* p0    = (half_t*)d_ws;           // fp16 h ping
    half_t* p1    = p0 + nd;                 // fp16 h pong
    half_t* agg16 = p1 + nd;                 // nd halfs; aliased as `pairs` during CSR build
    int*    rs    = (int*)(agg16 + nd);      // N+1 used, N+4 reserved
    int*    ssrc  = rs + (N + 4);            // byte offsets
    int*    gcnt  = ssrc + E;                // 256
    int*    gbs   = gcnt + 256;              // NB+1 (260 reserved)
    int*    gbc   = gbs + 260;               // 256
    half_t* Bf    = (half_t*)(gbc + 256);    // 6 layers * 16384 halfs

    int NB = (N + 511) >> 9;                 // 196 for N=100000
    int* pairs = (int*)agg16;                // consumed by kfinal before layer 0 writes agg16

    hipMemsetAsync(gcnt, 0, 256 * sizeof(int), stream);
    kbcnt<<<640, 256, 0, stream>>>(ei, E, gcnt);
    kbscan<<<1, 256, 0, stream>>>(gcnt, gbs, gbc, NB, E, rs, N);
    kbin<<<(E + 4095) / 4096, 256, 0, stream>>>(ei, E, gbc, pairs, NB);
    kfinal<<<NB, 256, 0, stream>>>(pairs, gbs, rs, ssrc, N);
    kprepw<<<(6 * 4 * 4 * 64 * 8 + 255) / 256, 256, 0, stream>>>(Wl, Wr, Bf);
    kcvt<<<((int)(nd / 4) + 255) / 256, 256, 0, stream>>>(x, p0, (int)(nd / 4));

    for (int l = 0; l < 6; ++l) {
        half_t* ih = (l & 1) ? p1 : p0;
        half_t* oh = (l & 1) ? p0 : p1;
        int last = (l == 5);
        kagg<<<(N + 31) / 32, 256, 0, stream>>>(ih, rs, ssrc, agg16, N);
        kgemm<<<512, 256, 0, stream>>>(agg16, ih, Bf + l * 16384, bl + l * 64,
                                       (float*)d_out, oh, N, last);
    }
}